// Round 6
// baseline (334.281 us; speedup 1.0000x reference)
//
#include <hip/hip_runtime.h>

// Problem: B=8, C=64, W=256, H=256, fp32.
// out[b,c,w,h] = sig(Wc@mean_wh(x)+bc)[b,c] * sig(Ww@mean_ch(x)+bw)[b,w] * sig(Wh@mean_cw(x)+bh)[b,h]
// Memory-bound: read 134MB + write 134MB -> ~41us pure-BW floor.
// R1: no atomics/reduces inside the load loop (in-order vmcnt).
// R2: out evicts x from L3 (MALL allocates regardless) -> nt stores; 58.5us.
// R4: few-block reduce of grid-wide partials = cross-XCD serial tail (+16us).
// R5: pool micro-variants are neutral-to-negative; 4-dispatch floor ~58.5us.
// R6: FUSE EVERYTHING: 1024 persistent blocks in 8 groups of 128 (one per b),
//     two per-group software barriers (counters memset each replay -- the
//     memset is inside the captured graph). Cross-block traffic is atomics +
//     agent-scope loads only (no dirty plain lines -> cheap fences).
//     Co-residency: 1024 blocks = half of 2048-block capacity at
//     __launch_bounds__(256,4) (LDS ~9KB/block) -> all blocks resident.

#define NB 8
#define NC 64
#define NW 256
#define NH 256

typedef float f4v __attribute__((ext_vector_type(4)));

// ws layout (floats):
// [0,16)      barrier counters (8 used, as unsigned)
// [16,528)    sum_c   [528,2576)  sum_w   [2576,4624) sum_h     (memset)
// [4624,5136) gate_c  [5136,7184) gate_w  [7184,9232) gate_h
#define WS_BAR    0
#define WS_SUMC   16
#define WS_SUMW   528
#define WS_SUMH   2576
#define WS_GATEC  4624
#define WS_GATEW  5136
#define WS_GATEH  7184

__device__ __forceinline__ float aload(const float* p) {
    return __hip_atomic_load(p, __ATOMIC_RELAXED, __HIP_MEMORY_SCOPE_AGENT);
}
__device__ __forceinline__ void astore(float* p, float v) {
    __hip_atomic_store(p, v, __ATOMIC_RELAXED, __HIP_MEMORY_SCOPE_AGENT);
}

// Per-group barrier: monotonic counter, two phases (targets 128 then 256).
__device__ __forceinline__ void group_barrier(unsigned* bar, unsigned target, int tid) {
    __syncthreads();
    if (tid == 0) {
        __threadfence();                 // drain prior (atomic) writes
        atomicAdd(bar, 1u);
        while (__hip_atomic_load(bar, __ATOMIC_RELAXED, __HIP_MEMORY_SCOPE_AGENT) < target)
            __builtin_amdgcn_s_sleep(2);
        __threadfence();
    }
    __syncthreads();
}

__global__ __launch_bounds__(256, 4) void fused_kernel(
        const float* __restrict__ x,
        const float* __restrict__ Wc, const float* __restrict__ bc_,
        const float* __restrict__ Ww, const float* __restrict__ bw_,
        const float* __restrict__ Wh, const float* __restrict__ bh_,
        float* __restrict__ ws, float* __restrict__ out) {
    int k    = blockIdx.x;          // 0..1023
    int b    = k >> 7;              // group = batch
    int j    = k & 127;             // block-in-group
    int bc   = b * 64 + (j >> 1);   // slice
    int half = j & 1;               // 128-row half
    int tid  = threadIdx.x;
    int wv   = tid >> 6;
    int lane = tid & 63;
    int wbase = half * 128;

    unsigned* bar = (unsigned*)(ws + WS_BAR) + b;
    float* sum_c = ws + WS_SUMC;
    float* sum_w = ws + WS_SUMW;
    float* sum_h = ws + WS_SUMH;
    float* gate_c = ws + WS_GATEC;
    float* gate_w = ws + WS_GATEW;
    float* gate_h = ws + WS_GATEH;

    __shared__ float rowsum[4][32];
    __shared__ __align__(16) float cols[4][NH];
    __shared__ float wpart[4];
    __shared__ float sc_lds[64], sw_lds[256], sh_lds[256];
    __shared__ __align__(16) float gh_lds[256];
    __shared__ float gw_lds[128];
    __shared__ float gc_lds;

    // ---- Phase 1: pool this half-slice (R2-proven pattern) ----
    const float4* xr = (const float4*)x + (size_t)bc * (NW * (NH / 4));
    float4 col = make_float4(0.f, 0.f, 0.f, 0.f);
    for (int kb = 0; kb < 32; kb += 8) {
        float4 v[8];
        #pragma unroll
        for (int i = 0; i < 8; ++i)
            v[i] = xr[(wbase + wv + 4 * (kb + i)) * (NH / 4) + lane];
        float rs[8];
        #pragma unroll
        for (int i = 0; i < 8; ++i) {
            col.x += v[i].x; col.y += v[i].y; col.z += v[i].z; col.w += v[i].w;
            rs[i] = (v[i].x + v[i].y) + (v[i].z + v[i].w);
        }
        #pragma unroll
        for (int off = 32; off; off >>= 1) {
            #pragma unroll
            for (int i = 0; i < 8; ++i) rs[i] += __shfl_xor(rs[i], off);
        }
        #pragma unroll
        for (int i = 0; i < 8; ++i)
            if (lane == i) rowsum[wv][kb + i] = rs[i];
    }
    cols[wv][lane * 4 + 0] = col.x;
    cols[wv][lane * 4 + 1] = col.y;
    cols[wv][lane * 4 + 2] = col.z;
    cols[wv][lane * 4 + 3] = col.w;
    __syncthreads();

    float cv = cols[0][tid] + cols[1][tid] + cols[2][tid] + cols[3][tid];
    atomicAdd(&sum_h[b * NH + tid], cv);
    if (tid < 128)
        atomicAdd(&sum_w[b * NW + wbase + tid], rowsum[tid & 3][tid >> 2]);
    float t = cv;
    #pragma unroll
    for (int off = 32; off; off >>= 1) t += __shfl_xor(t, off);
    if (lane == 0) wpart[wv] = t;
    __syncthreads();
    if (tid == 0) atomicAdd(&sum_c[bc], wpart[0] + wpart[1] + wpart[2] + wpart[3]);

    // ---- Barrier 1: group's sums complete ----
    group_barrier(bar, 128u, tid);

    // ---- Phase 2: gates. 512 waves/group cover 576 dots. ----
    if (tid < 64)  sc_lds[tid] = aload(&sum_c[b * 64 + tid]);
    sw_lds[tid] = aload(&sum_w[b * 256 + tid]);
    sh_lds[tid] = aload(&sum_h[b * 256 + tid]);
    __syncthreads();

    int g = (j << 2) | wv;          // group-local wave id, 0..511
    #pragma unroll
    for (int rep = 0; rep < 2; ++rep) {
        int id = rep == 0 ? g : 512 + g;
        if (rep == 1 && g >= 64) break;
        float acc, bias;
        float* dst;
        if (id < 64) {                      // gate_c[o]: dot-64
            int o = id;
            acc = Wc[o * 64 + lane] * sc_lds[lane] * (1.f / 65536.f);
            bias = bc_[o];
            dst = &gate_c[b * 64 + o];
        } else if (id < 320) {              // gate_w[o]: dot-256
            int o = id - 64;
            acc = 0.f;
            #pragma unroll
            for (int m = 0; m < 4; ++m)
                acc += Ww[o * 256 + lane + 64 * m] * sw_lds[lane + 64 * m];
            acc *= (1.f / 16384.f);
            bias = bw_[o];
            dst = &gate_w[b * 256 + o];
        } else {                            // gate_h[o]: dot-256
            int o = id - 320;
            acc = 0.f;
            #pragma unroll
            for (int m = 0; m < 4; ++m)
                acc += Wh[o * 256 + lane + 64 * m] * sh_lds[lane + 64 * m];
            acc *= (1.f / 16384.f);
            bias = bh_[o];
            dst = &gate_h[b * 256 + o];
        }
        #pragma unroll
        for (int off = 32; off; off >>= 1) acc += __shfl_xor(acc, off);
        if (lane == 0) astore(dst, 1.f / (1.f + expf(-(acc + bias))));
    }

    // ---- Barrier 2: group's gates complete ----
    group_barrier(bar, 256u, tid);

    // ---- Phase 3: write this half-slice ----
    gh_lds[tid] = aload(&gate_h[b * 256 + tid]);
    if (tid < 128) gw_lds[tid] = aload(&gate_w[b * 256 + wbase + tid]);
    if (tid == 0)  gc_lds = aload(&gate_c[bc]);
    __syncthreads();

    float gcv = gc_lds;
    int h4 = tid & 63;
    float4 gh = ((const float4*)gh_lds)[h4];
    float4* dst = (float4*)out + (size_t)bc * 16384 + (size_t)wbase * 64 + h4;
    #pragma unroll 8
    for (int r = wv; r < 128; r += 4) {
        float gg = gcv * gw_lds[r];
        f4v val = {gg * gh.x, gg * gh.y, gg * gh.z, gg * gh.w};
        __builtin_nontemporal_store(val, (f4v*)(dst + (size_t)r * 64));
    }
}

extern "C" void kernel_launch(void* const* d_in, const int* in_sizes, int n_in,
                              void* d_out, int out_size, void* d_ws, size_t ws_size,
                              hipStream_t stream) {
    const float* x   = (const float*)d_in[0];
    const float* Wc  = (const float*)d_in[1];
    const float* bc_ = (const float*)d_in[2];
    const float* Ww  = (const float*)d_in[3];
    const float* bw_ = (const float*)d_in[4];
    const float* Wh  = (const float*)d_in[5];
    const float* bh_ = (const float*)d_in[6];
    float* ws = (float*)d_ws;

    // zero barrier counters + sum accumulators (runs every graph replay)
    hipMemsetAsync(ws, 0, 4624 * sizeof(float), stream);

    fused_kernel<<<1024, 256, 0, stream>>>(x, Wc, bc_, Ww, bw_, Wh, bh_,
                                           ws, (float*)d_out);
}

// Round 7
// 57.247 us; speedup vs baseline: 5.8393x; 5.8393x over previous
//
#include <hip/hip_runtime.h>

// Problem: B=8, C=64, W=256, H=256, fp32.
// out[b,c,w,h] = sig(Wc@mean_wh(x)+bc)[b,c] * sig(Ww@mean_ch(x)+bw)[b,w] * sig(Wh@mean_cw(x)+bh)[b,h]
// Memory-bound: read 134MB + write 134MB.
// R1: no atomics/reduces inside the load loop (in-order vmcnt).
// R2/R3: best = 58.5us; atomics+memset == partials+reduce. out ~20us (write
//        ceiling), gates ~3us, pool ~30us (134MB @ 4.5TB/s -- the gap).
// R4: few-block consumers of grid-wide dirty partials = cross-XCD tail. NEVER.
// R6: persistent fusion + spin barriers = 334us disaster. NEVER.
// R7: isolate pool occupancy: 1024 blocks x 512 threads (32 waves/CU, 2x R2),
//     same interleaved-row 8-deep pattern, same atomic count, nt loads.

#define NB 8
#define NC 64
#define NW 256
#define NH 256

typedef float f4v __attribute__((ext_vector_type(4)));

// ws float layout:
// [0,512)      sum_c   [512,2560) sum_w   [2560,4608) sum_h   (memset each call)
// [4608,5120)  gate_c  [5120,7168) gate_w [7168,9216) gate_h

__global__ __launch_bounds__(512) void pool_kernel(const float* __restrict__ x,
                                                   float* __restrict__ ws) {
    float* sum_c = ws;
    float* sum_w = ws + 512;
    float* sum_h = ws + 2560;

    int k    = blockIdx.x;         // 0..1023
    int bc   = k >> 1;             // b*64 + c
    int half = k & 1;              // 128-row half
    int b    = bc >> 6;
    int tid  = threadIdx.x;        // 0..511
    int wv   = tid >> 6;           // wave 0..7
    int lane = tid & 63;
    int wbase = half * 128;

    const f4v* xr = (const f4v*)x + (size_t)bc * (NW * (NH / 4));

    __shared__ float rowsum[8][16];   // [wave][j] : row wbase + wv + 8j
    __shared__ float cols[8][NH];     // per-wave column partials
    __shared__ float wpart[4];

    f4v col = {0.f, 0.f, 0.f, 0.f};
    // wave wv owns rows wbase + wv + 8j, j=0..15; two batches of 8 in flight.
    for (int jb = 0; jb < 16; jb += 8) {
        f4v v[8];
        #pragma unroll
        for (int i = 0; i < 8; ++i)
            v[i] = __builtin_nontemporal_load(
                xr + (size_t)(wbase + wv + 8 * (jb + i)) * (NH / 4) + lane);
        float rs[8];
        #pragma unroll
        for (int i = 0; i < 8; ++i) {
            col += v[i];
            rs[i] = (v[i][0] + v[i][1]) + (v[i][2] + v[i][3]);
        }
        #pragma unroll
        for (int off = 32; off; off >>= 1) {
            #pragma unroll
            for (int i = 0; i < 8; ++i) rs[i] += __shfl_xor(rs[i], off);
        }
        #pragma unroll
        for (int i = 0; i < 8; ++i)
            if (lane == i) rowsum[wv][jb + i] = rs[i];
    }

    cols[wv][lane * 4 + 0] = col[0];
    cols[wv][lane * 4 + 1] = col[1];
    cols[wv][lane * 4 + 2] = col[2];
    cols[wv][lane * 4 + 3] = col[3];
    __syncthreads();

    // threads 0..255: column h=tid; one coalesced atomic per column
    if (tid < 256) {
        float cv = 0.f;
        #pragma unroll
        for (int w8 = 0; w8 < 8; ++w8) cv += cols[w8][tid];
        atomicAdd(&sum_h[b * NH + tid], cv);

        // block total -> sum_c (waves 0..3 of the cv values)
        float t = cv;
        #pragma unroll
        for (int off = 32; off; off >>= 1) t += __shfl_xor(t, off);
        if (lane == 0) wpart[wv] = t;
    }
    // threads 0..127: row r=tid of this half -> wave r&7, slot r>>3
    if (tid < 128)
        atomicAdd(&sum_w[b * NW + wbase + tid], rowsum[tid & 7][tid >> 3]);
    __syncthreads();
    if (tid == 0)
        atomicAdd(&sum_c[bc], (wpart[0] + wpart[1]) + (wpart[2] + wpart[3]));
}

__global__ __launch_bounds__(256) void gates_kernel(const float* __restrict__ Wc, const float* __restrict__ bc_,
                                                    const float* __restrict__ Ww, const float* __restrict__ bw_,
                                                    const float* __restrict__ Wh, const float* __restrict__ bh_,
                                                    float* __restrict__ ws) {
    const float* sum_c = ws;
    const float* sum_w = ws + 512;
    const float* sum_h = ws + 2560;
    float* gate_c = ws + 4608;
    float* gate_w = ws + 5120;
    float* gate_h = ws + 7168;

    int j = blockIdx.x * 4 + (threadIdx.x >> 6);  // global wave id, 0..4607
    int lane = threadIdx.x & 63;

    float acc = 0.f, bias;
    float* dst;
    if (j < 512) {                                 // c-gate: dot length 64
        int b = j >> 6, o = j & 63;
        acc = Wc[o * 64 + lane] * sum_c[b * 64 + lane] * (1.f / 65536.f);
        bias = bc_[o];
        dst = &gate_c[j];
    } else if (j < 2560) {                         // w-gate: dot length 256
        int j2 = j - 512;
        int b = j2 >> 8, o = j2 & 255;
        const float* wr = Ww + o * 256;
        const float* sr = sum_w + b * 256;
        #pragma unroll
        for (int m = 0; m < 4; ++m) acc += wr[lane + 64 * m] * sr[lane + 64 * m];
        acc *= (1.f / 16384.f);
        bias = bw_[o];
        dst = &gate_w[j2];
    } else {                                       // h-gate: dot length 256
        int j2 = j - 2560;
        int b = j2 >> 8, o = j2 & 255;
        const float* wr = Wh + o * 256;
        const float* sr = sum_h + b * 256;
        #pragma unroll
        for (int m = 0; m < 4; ++m) acc += wr[lane + 64 * m] * sr[lane + 64 * m];
        acc *= (1.f / 16384.f);
        bias = bh_[o];
        dst = &gate_h[j2];
    }
    #pragma unroll
    for (int off = 32; off; off >>= 1) acc += __shfl_xor(acc, off);
    if (lane == 0) *dst = 1.f / (1.f + expf(-(acc + bias)));
}

__global__ __launch_bounds__(256) void out_kernel(const float* __restrict__ ws,
                                                  float* __restrict__ out) {
    const float* gate_c = ws + 4608;
    const float* gate_w = ws + 5120;
    const float4* gate_h4 = (const float4*)(ws + 7168);

    const size_t N4 = (size_t)NB * NC * NW * (NH / 4);  // 8388608
    size_t stride = (size_t)gridDim.x * blockDim.x;
    for (size_t i = (size_t)blockIdx.x * blockDim.x + threadIdx.x; i < N4; i += stride) {
        int h4 = (int)(i & 63);          // H/4 = 64
        size_t row = i >> 6;
        int w = (int)(row & 255);        // W = 256
        size_t bcr = row >> 8;
        int c = (int)(bcr & 63);         // C = 64
        int b = (int)(bcr >> 6);
        float g = gate_c[b * 64 + c] * gate_w[b * 256 + w];
        float4 gh = gate_h4[b * 64 + h4];
        f4v val = {g * gh.x, g * gh.y, g * gh.z, g * gh.w};
        __builtin_nontemporal_store(val, (f4v*)(out + 4 * i));
    }
}

extern "C" void kernel_launch(void* const* d_in, const int* in_sizes, int n_in,
                              void* d_out, int out_size, void* d_ws, size_t ws_size,
                              hipStream_t stream) {
    const float* x   = (const float*)d_in[0];
    const float* Wc  = (const float*)d_in[1];
    const float* bc_ = (const float*)d_in[2];
    const float* Ww  = (const float*)d_in[3];
    const float* bw_ = (const float*)d_in[4];
    const float* Wh  = (const float*)d_in[5];
    const float* bh_ = (const float*)d_in[6];
    float* ws = (float*)d_ws;

    // zero the atomic accumulators (sum_c, sum_w, sum_h)
    hipMemsetAsync(ws, 0, 4608 * sizeof(float), stream);

    pool_kernel<<<1024, 512, 0, stream>>>(x, ws);
    gates_kernel<<<4608 / 4, 256, 0, stream>>>(Wc, bc_, Ww, bw_, Wh, bh_, ws);
    out_kernel<<<2048, 256, 0, stream>>>(ws, (float*)d_out);
}